// Round 5
// baseline (297.155 us; speedup 1.0000x reference)
//
#include <hip/hip_runtime.h>
#include <hip/hip_bf16.h>

typedef __bf16 bf16_t;
typedef __bf16 bf16x8 __attribute__((ext_vector_type(8)));
typedef __bf16 bf16x4 __attribute__((ext_vector_type(4)));
typedef float f32x4 __attribute__((ext_vector_type(4)));
typedef float f32x16 __attribute__((ext_vector_type(16)));
typedef unsigned int u32x4 __attribute__((ext_vector_type(4)));

#define AS1(p) ((const __attribute__((address_space(1))) void*)(p))
#define AS3(p) ((__attribute__((address_space(3))) void*)(p))

// scale = HEAD_DIM^-0.5 * log2(e), folded into Q at QKV-GEMM epilogue
#define QSCALE 0.1803368801111204f

// ---------------- cast X fp32 -> bf16 ----------------
__global__ void cast_x_kernel(const float* __restrict__ X, bf16_t* __restrict__ Xb) {
  int i = (blockIdx.x * 256 + threadIdx.x) * 4;
  float4 v = *(const float4*)(X + i);
  bf16x4 o;
  o[0] = (bf16_t)v.x; o[1] = (bf16_t)v.y; o[2] = (bf16_t)v.z; o[3] = (bf16_t)v.w;
  *(bf16x4*)(Xb + i) = o;
}

// ---------------- transpose + cast W [K][N] fp32 -> Wt [N][K] bf16 ----------------
__global__ void transpose_cast_kernel(const float* __restrict__ W, bf16_t* __restrict__ Wt,
                                      int K, int N) {
  __shared__ float tile[32][33];
  int n0 = blockIdx.x * 32, k0 = blockIdx.y * 32;
  int tx = threadIdx.x, ty = threadIdx.y;
  for (int r = ty; r < 32; r += 8)
    tile[r][tx] = W[(size_t)(k0 + r) * N + n0 + tx];
  __syncthreads();
  for (int r = ty; r < 32; r += 8)
    Wt[(size_t)(n0 + r) * K + k0 + tx] = (bf16_t)tile[tx][r];
}

// ---------------- QKV GEMM: C[8192,3072] = Xb[8192,1024] @ Wt[3072,1024]^T ----------------
// Q,K written [b,h,s,d] (Q pre-scaled by QSCALE); V written TRANSPOSED [b,h,d,s].
__global__ __launch_bounds__(256) void gemm_qkv_kernel(
    const bf16_t* __restrict__ A, const bf16_t* __restrict__ Bt,
    bf16_t* __restrict__ Qb, bf16_t* __restrict__ Kb, bf16_t* __restrict__ Vt) {
  __shared__ __align__(16) bf16_t As[128 * 32];
  __shared__ __align__(16) bf16_t Bs[128 * 32];
  const int tid = threadIdx.x;
  const int lane = tid & 63, wave = tid >> 6;
  const int quad = lane >> 4, l15 = lane & 15;
  const int wr = wave >> 1, wc = wave & 1;
  const int m0 = blockIdx.x * 128, n0 = blockIdx.y * 128;
  f32x4 acc[4][4];
  const f32x4 vzero = {0.f, 0.f, 0.f, 0.f};
#pragma unroll
  for (int i = 0; i < 4; i++)
#pragma unroll
    for (int j = 0; j < 4; j++) acc[i][j] = vzero;

  for (int kb = 0; kb < 1024; kb += 32) {
    __syncthreads();
#pragma unroll
    for (int i = 0; i < 2; i++) {
      int c = i * 256 + tid;
      int row = c >> 2, kc = c & 3;
      __builtin_amdgcn_global_load_lds(AS1(A + (size_t)(m0 + row) * 1024 + kb + kc * 8),
                                       AS3(As + c * 8), 16, 0, 0);
    }
#pragma unroll
    for (int i = 0; i < 2; i++) {
      int c = i * 256 + tid;
      int row = c >> 2, kc = c & 3;
      __builtin_amdgcn_global_load_lds(AS1(Bt + (size_t)(n0 + row) * 1024 + kb + kc * 8),
                                       AS3(Bs + c * 8), 16, 0, 0);
    }
    __builtin_amdgcn_s_waitcnt(0);
    __syncthreads();
    bf16x8 af[4], bfr[4];
#pragma unroll
    for (int t = 0; t < 4; t++) {
      af[t]  = *(const bf16x8*)(As + (wr * 64 + t * 16 + l15) * 32 + quad * 8);
      bfr[t] = *(const bf16x8*)(Bs + (wc * 64 + t * 16 + l15) * 32 + quad * 8);
    }
#pragma unroll
    for (int mt = 0; mt < 4; mt++)
#pragma unroll
      for (int nt = 0; nt < 4; nt++)
        acc[mt][nt] = __builtin_amdgcn_mfma_f32_16x16x32_bf16(af[mt], bfr[nt], acc[mt][nt], 0, 0, 0);
  }
  // C layout: col=lane&15, row=quad*4+reg
#pragma unroll
  for (int nt = 0; nt < 4; nt++) {
    int gn = n0 + wc * 64 + nt * 16 + l15;
    int which = gn >> 10;   // 0=Q, 1=K, 2=V (uniform across lanes per nt)
    int rem = gn & 1023;
    int hh = rem >> 6, dd = rem & 63;
    if (which == 2) {
      // V transposed: Vt[b][h][dd][s], r-dim is consecutive s -> 8B vector store
#pragma unroll
      for (int mt = 0; mt < 4; mt++) {
        int gm0 = m0 + wr * 64 + mt * 16 + quad * 4;
        int b = gm0 >> 11, s = gm0 & 2047;
        bf16x4 o;
#pragma unroll
        for (int r = 0; r < 4; r++) o[r] = (bf16_t)acc[mt][nt][r];
        *(bf16x4*)(Vt + ((size_t)((b << 4) + hh) * 64 + dd) * 2048 + s) = o;
      }
    } else {
      bf16_t* dst = (which == 0) ? Qb : Kb;
      float scl = (which == 0) ? QSCALE : 1.0f;
#pragma unroll
      for (int mt = 0; mt < 4; mt++) {
#pragma unroll
        for (int r = 0; r < 4; r++) {
          int gm = m0 + wr * 64 + mt * 16 + quad * 4 + r;
          int b = gm >> 11, s = gm & 2047;
          dst[((size_t)((b << 4) + hh) * 2048 + s) * 64 + dd] = (bf16_t)(acc[mt][nt][r] * scl);
        }
      }
    }
  }
}

// pack two f32 into one u32 of 2 bf16
__device__ inline unsigned pack_bf16x2(float a, float b) {
  unsigned short lo = __builtin_bit_cast(unsigned short, (bf16_t)a);
  unsigned short hi = __builtin_bit_cast(unsigned short, (bf16_t)b);
  return (unsigned)lo | ((unsigned)hi << 16);
}

// ---------------- Flash attention, causal, no-max softmax, in-register P ----------------
// Structure as round 4 (verified): 1024 blocks = 64 bh x 16 Q-tiles, bh in low 6 bits
// (per-bh XCD L2 affinity: FETCH 146->25 MB), qb descending; KVBLK=64, LDS 32 KB,
// 4 blocks/CU. Datapath: swapped QK^T with sigma-permuted K rows -> softmax/mask/pack
// fully in-register, L on the matrix pipe.
// NEW: the two 32-k bodies of each 64-k iteration are FUSED into one straight-line
// scheduling region (independent sc0/sc1 accumulators, one setprio pair, uniform
// branch for masked exp) so body-1's QK-MFMA latency hides under body-0's
// softmax+PV and vice versa. Attacks the measured 5x latency-stall at 2.5 waves/SIMD.
__global__ __launch_bounds__(256, 4) void attn_kernel(
    const bf16_t* __restrict__ Qg_, const bf16_t* __restrict__ Kg_,
    const bf16_t* __restrict__ Vtg_, bf16_t* __restrict__ ctx) {
  __shared__ __align__(16) bf16_t Ksm[2][64 * 64];  // [k][d], 16B slots XOR row&7  (8 KB each)
  __shared__ __align__(16) bf16_t Vsm[2][64 * 64];  // [d][s], 16B slots XOR d&7    (8 KB each)
  const int tid = threadIdx.x;
  const int lane = tid & 63, w = tid >> 6;
  const int l31 = lane & 31, hl = lane >> 5;
  // sigma: swap bits 2 and 3 of l31 — K A-operand row permutation
  const int krow = (l31 & 0x13) | ((l31 & 4) << 1) | ((l31 & 8) >> 1);

  const int bh = blockIdx.x & 63;          // low bits -> XCD = bh%8
  const int qb = 15 - (blockIdx.x >> 6);   // big Q-tiles dispatched first
  const int b = bh >> 4, h = bh & 15;
  const size_t base = (size_t)bh * 2048 * 64;
  const bf16_t* Qg = Qg_ + base;
  const bf16_t* Kg = Kg_ + base;
  const bf16_t* Vtg = Vtg_ + base;  // [d][s]

  // per-lane LDS element offsets (nt adds a compile-time term under unroll)
  int kadr[4];
#pragma unroll
  for (int kk = 0; kk < 4; kk++)
    kadr[kk] = (krow * 8 + ((kk * 2 + hl) ^ (krow & 7))) * 8;
  int vadr[2];
#pragma unroll
  for (int nv = 0; nv < 2; nv++) {
    const int dr = nv * 32 + l31;
    vadr[nv] = (dr * 8 + (hl ^ (dr & 7))) * 8;
  }

  auto stage_kv = [&](int bb, int jn) {
#pragma unroll
    for (int i = 0; i < 2; i++) {
      int slot = i * 256 + tid;                       // 512 16B slots = 64x64 bf16
      int row = slot >> 3, c = (slot & 7) ^ (row & 7);
      __builtin_amdgcn_global_load_lds(AS1(Kg + ((size_t)jn * 64 + row) * 64 + c * 8),
                                       AS3(&Ksm[bb][0] + slot * 8), 16, 0, 0);
    }
#pragma unroll
    for (int i = 0; i < 2; i++) {
      int slot = i * 256 + tid;                       // 512 16B slots = 64x64 bf16
      int d = slot >> 3, c = (slot & 7) ^ (d & 7);
      __builtin_amdgcn_global_load_lds(AS1(Vtg + (size_t)d * 2048 + jn * 64 + c * 8),
                                       AS3(&Vsm[bb][0] + slot * 8), 16, 0, 0);
    }
  };

  bf16x8 bone;
#pragma unroll
  for (int e = 0; e < 8; e++) bone[e] = (bf16_t)1.0f;
  f32x16 zc;
#pragma unroll
  for (int e = 0; e < 16; e++) zc[e] = 0.f;

  const int J = 2 * (qb + 1);              // 64-wide KV iters
  const int qrel = qb * 128 + w * 32;      // wave's first q row (global)
  const int qg = qrel + l31;               // this lane's q-row (softmax axis)

  // Q fragments (B-operand of 32x32x16): n=l31=q, k = hl*8+e
  bf16x8 aq[4];
#pragma unroll
  for (int kk = 0; kk < 4; kk++)
    aq[kk] = *(const bf16x8*)(Qg + (size_t)qg * 64 + kk * 16 + hl * 8);

  f32x16 Oacc[2], Lacc;
#pragma unroll
  for (int e = 0; e < 16; e++) { Oacc[0][e] = 0.f; Oacc[1][e] = 0.f; Lacc[e] = 0.f; }

  int cur = 0;
  stage_kv(0, 0);

  for (int j = 0; j < J; j++) {
    // stage-j DMA (issued last iter, hidden under compute) must be in LDS;
    // per-thread vmcnt(0) BEFORE the barrier covers other waves' reads too
    asm volatile("s_waitcnt vmcnt(0)" ::: "memory");
    __syncthreads();
    if (j + 1 < J) stage_kv(cur ^ 1, j + 1);  // flies during compute

    const bf16_t* Kb = &Ksm[cur][0];
    const bf16_t* Vb = &Vsm[cur][0];
    const int k0 = j * 64;

    // helpers (all inlined; nt/indices fold to compile-time constants)
    auto qkchain = [&](int nt) {
      bf16x8 a0 = *(const bf16x8*)(Kb + nt * 2048 + kadr[0]);
      bf16x8 a1 = *(const bf16x8*)(Kb + nt * 2048 + kadr[1]);
      bf16x8 a2 = *(const bf16x8*)(Kb + nt * 2048 + kadr[2]);
      bf16x8 a3 = *(const bf16x8*)(Kb + nt * 2048 + kadr[3]);
      f32x16 sc = __builtin_amdgcn_mfma_f32_32x32x16_bf16(a0, aq[0], zc, 0, 0, 0);
      sc = __builtin_amdgcn_mfma_f32_32x32x16_bf16(a1, aq[1], sc, 0, 0, 0);
      sc = __builtin_amdgcn_mfma_f32_32x32x16_bf16(a2, aq[2], sc, 0, 0, 0);
      sc = __builtin_amdgcn_mfma_f32_32x32x16_bf16(a3, aq[3], sc, 0, 0, 0);
      return sc;
    };
    auto smpack = [&](const f32x16& sc, bool masked, bf16x8& pa0, bf16x8& pa1) {
      float p[16];
      if (masked) {
#pragma unroll
        for (int r = 0; r < 16; r++) {
          const int koff = hl * 8 + (r & 7) + 16 * (r >> 3);
          p[r] = (koff > l31) ? 0.f : __builtin_exp2f(sc[r]);
        }
      } else {
#pragma unroll
        for (int r = 0; r < 16; r++) p[r] = __builtin_exp2f(sc[r]);
      }
      u32x4 w0, w1;
      w0[0] = pack_bf16x2(p[0], p[1]);   w0[1] = pack_bf16x2(p[2], p[3]);
      w0[2] = pack_bf16x2(p[4], p[5]);   w0[3] = pack_bf16x2(p[6], p[7]);
      w1[0] = pack_bf16x2(p[8], p[9]);   w1[1] = pack_bf16x2(p[10], p[11]);
      w1[2] = pack_bf16x2(p[12], p[13]); w1[3] = pack_bf16x2(p[14], p[15]);
      pa0 = __builtin_bit_cast(bf16x8, w0);  // k-offs nt*32 + 0..15
      pa1 = __builtin_bit_cast(bf16x8, w1);  // k-offs nt*32 + 16..31
    };
    auto pv = [&](int nt, bf16x8 pa0, bf16x8 pa1) {
      Lacc = __builtin_amdgcn_mfma_f32_32x32x16_bf16(pa0, bone, Lacc, 0, 0, 0);
      Lacc = __builtin_amdgcn_mfma_f32_32x32x16_bf16(pa1, bone, Lacc, 0, 0, 0);
#pragma unroll
      for (int nv = 0; nv < 2; nv++) {
        bf16x8 bv0 = *(const bf16x8*)(Vb + (vadr[nv] ^ ((nt * 4 + 0) * 8)));
        Oacc[nv] = __builtin_amdgcn_mfma_f32_32x32x16_bf16(pa0, bv0, Oacc[nv], 0, 0, 0);
        bf16x8 bv1 = *(const bf16x8*)(Vb + (vadr[nv] ^ ((nt * 4 + 2) * 8)));
        Oacc[nv] = __builtin_amdgcn_mfma_f32_32x32x16_bf16(pa1, bv1, Oacc[nv], 0, 0, 0);
      }
    };

    const bool a0 = (k0 <= qrel);            // body nt=0 active
    const bool a1 = (k0 + 32 <= qrel);       // body nt=1 active
    if (a1) {
      // FUSED fast path: both bodies in one scheduling region. nt=0 is never
      // masked here (k0 < qrel); nt=1 masked iff k0+32 == qrel.
      __builtin_amdgcn_s_setprio(1);
      f32x16 sc0 = qkchain(0);
      f32x16 sc1 = qkchain(1);
      bf16x8 pa00, pa01, pa10, pa11;
      smpack(sc0, false, pa00, pa01);        // runs while sc1 chain drains
      pv(0, pa00, pa01);
      smpack(sc1, k0 + 32 == qrel, pa10, pa11);  // exp2 under pv(0)'s MFMAs
      pv(1, pa10, pa11);
      __builtin_amdgcn_s_setprio(0);
    } else if (a0) {
      // single-body tail: k0 == qrel (qrel mult of 32, k0 mult of 64) -> masked
      __builtin_amdgcn_s_setprio(1);
      f32x16 sc0 = qkchain(0);
      bf16x8 pa00, pa01;
      smpack(sc0, true, pa00, pa01);
      pv(0, pa00, pa01);
      __builtin_amdgcn_s_setprio(0);
    }
    cur ^= 1;
  }

  // epilogue: Lacc rows coincide with Oacc rows -> direct rcp, no shuffles/LDS
#pragma unroll
  for (int r = 0; r < 16; r++) {
    const int crow = (r & 3) + 8 * (r >> 2) + 4 * hl;
    const float rl = __builtin_amdgcn_rcpf(Lacc[r]);
    const int qrow = qb * 128 + w * 32 + crow;
#pragma unroll
    for (int nv = 0; nv < 2; nv++)
      ctx[((size_t)b * 2048 + qrow) * 1024 + h * 64 + nv * 32 + l31] =
          (bf16_t)(Oacc[nv][r] * rl);
  }
}

// ---------------- out proj: out[8192,1024] = ctx @ Wout^T + b ----------------
__global__ __launch_bounds__(256) void gemm_out_kernel(
    const bf16_t* __restrict__ A, const bf16_t* __restrict__ Bt,
    const float* __restrict__ bias, float* __restrict__ out) {
  __shared__ __align__(16) bf16_t As[128 * 32];
  __shared__ __align__(16) bf16_t Bs[128 * 32];
  const int tid = threadIdx.x;
  const int lane = tid & 63, wave = tid >> 6;
  const int quad = lane >> 4, l15 = lane & 15;
  const int wr = wave >> 1, wc = wave & 1;
  const int m0 = blockIdx.x * 128, n0 = blockIdx.y * 128;
  f32x4 acc[4][4];
  const f32x4 vzero = {0.f, 0.f, 0.f, 0.f};
#pragma unroll
  for (int i = 0; i < 4; i++)
#pragma unroll
    for (int j = 0; j < 4; j++) acc[i][j] = vzero;

  for (int kb = 0; kb < 1024; kb += 32) {
    __syncthreads();
#pragma unroll
    for (int i = 0; i < 2; i++) {
      int c = i * 256 + tid;
      int row = c >> 2, kc = c & 3;
      __builtin_amdgcn_global_load_lds(AS1(A + (size_t)(m0 + row) * 1024 + kb + kc * 8),
                                       AS3(As + c * 8), 16, 0, 0);
    }
#pragma unroll
    for (int i = 0; i < 2; i++) {
      int c = i * 256 + tid;
      int row = c >> 2, kc = c & 3;
      __builtin_amdgcn_global_load_lds(AS1(Bt + (size_t)(n0 + row) * 1024 + kb + kc * 8),
                                       AS3(Bs + c * 8), 16, 0, 0);
    }
    __builtin_amdgcn_s_waitcnt(0);
    __syncthreads();
    bf16x8 af[4], bfr[4];
#pragma unroll
    for (int t = 0; t < 4; t++) {
      af[t]  = *(const bf16x8*)(As + (wr * 64 + t * 16 + l15) * 32 + quad * 8);
      bfr[t] = *(const bf16x8*)(Bs + (wc * 64 + t * 16 + l15) * 32 + quad * 8);
    }
#pragma unroll
    for (int mt = 0; mt < 4; mt++)
#pragma unroll
      for (int nt = 0; nt < 4; nt++)
        acc[mt][nt] = __builtin_amdgcn_mfma_f32_16x16x32_bf16(af[mt], bfr[nt], acc[mt][nt], 0, 0, 0);
  }
#pragma unroll
  for (int nt = 0; nt < 4; nt++) {
    int gn = n0 + wc * 64 + nt * 16 + l15;
    float bv = bias[gn];
#pragma unroll
    for (int mt = 0; mt < 4; mt++) {
#pragma unroll
      for (int r = 0; r < 4; r++) {
        int gm = m0 + wr * 64 + mt * 16 + quad * 4 + r;
        out[(size_t)gm * 1024 + gn] = acc[mt][nt][r] + bv;
      }
    }
  }
}

extern "C" void kernel_launch(void* const* d_in, const int* in_sizes, int n_in,
                              void* d_out, int out_size, void* d_ws, size_t ws_size,
                              hipStream_t stream) {
  (void)in_sizes; (void)n_in; (void)out_size; (void)ws_size;
  const float* X     = (const float*)d_in[0];  // [4,2048,1024]
  const float* W_qkv = (const float*)d_in[1];  // [1024,3072]
  const float* W_out = (const float*)d_in[2];  // [1024,1024]
  const float* b_out = (const float*)d_in[3];  // [1024]
  float* out = (float*)d_out;                  // [4,2048,1024] fp32

  char* ws = (char*)d_ws;
  bf16_t* Xb    = (bf16_t*)(ws);               // 16 MB
  bf16_t* Wqkvt = (bf16_t*)(ws + 16777216);    // 6 MB   [3072][1024]
  bf16_t* Woutt = (bf16_t*)(ws + 23068672);    // 2 MB   [1024][1024]
  bf16_t* Qb    = (bf16_t*)(ws + 25165824);    // 16 MB  [b,h,s,d]
  bf16_t* Kb    = (bf16_t*)(ws + 41943040);    // 16 MB  [b,h,s,d]
  bf16_t* Vt    = (bf16_t*)(ws + 58720256);    // 16 MB  [b,h,d,s] (written directly by GEMM)
  bf16_t* ctx   = (bf16_t*)(ws + 75497472);    // 16 MB  [b,s,1024]

  cast_x_kernel<<<8192, 256, 0, stream>>>(X, Xb);
  transpose_cast_kernel<<<dim3(96, 32), dim3(32, 8), 0, stream>>>(W_qkv, Wqkvt, 1024, 3072);
  transpose_cast_kernel<<<dim3(32, 32), dim3(32, 8), 0, stream>>>(W_out, Woutt, 1024, 1024);
  gemm_qkv_kernel<<<dim3(64, 24), 256, 0, stream>>>(Xb, Wqkvt, Qb, Kb, Vt);
  attn_kernel<<<dim3(1024), 256, 0, stream>>>(Qb, Kb, Vt, ctx);
  gemm_out_kernel<<<dim3(64, 8), 256, 0, stream>>>(ctx, Woutt, b_out, out);
}

// Round 6
// 252.207 us; speedup vs baseline: 1.1782x; 1.1782x over previous
//
#include <hip/hip_runtime.h>
#include <hip/hip_bf16.h>

typedef __bf16 bf16_t;
typedef __bf16 bf16x8 __attribute__((ext_vector_type(8)));
typedef __bf16 bf16x4 __attribute__((ext_vector_type(4)));
typedef float f32x4 __attribute__((ext_vector_type(4)));
typedef float f32x16 __attribute__((ext_vector_type(16)));
typedef unsigned int u32x4 __attribute__((ext_vector_type(4)));

#define AS1(p) ((const __attribute__((address_space(1))) void*)(p))
#define AS3(p) ((__attribute__((address_space(3))) void*)(p))

// scale = HEAD_DIM^-0.5 * log2(e), folded into Q at QKV-GEMM epilogue
#define QSCALE 0.1803368801111204f

// ---------------- cast X fp32 -> bf16 ----------------
__global__ void cast_x_kernel(const float* __restrict__ X, bf16_t* __restrict__ Xb) {
  int i = (blockIdx.x * 256 + threadIdx.x) * 4;
  float4 v = *(const float4*)(X + i);
  bf16x4 o;
  o[0] = (bf16_t)v.x; o[1] = (bf16_t)v.y; o[2] = (bf16_t)v.z; o[3] = (bf16_t)v.w;
  *(bf16x4*)(Xb + i) = o;
}

// ---------------- transpose + cast W [K][N] fp32 -> Wt [N][K] bf16 ----------------
__global__ void transpose_cast_kernel(const float* __restrict__ W, bf16_t* __restrict__ Wt,
                                      int K, int N) {
  __shared__ float tile[32][33];
  int n0 = blockIdx.x * 32, k0 = blockIdx.y * 32;
  int tx = threadIdx.x, ty = threadIdx.y;
  for (int r = ty; r < 32; r += 8)
    tile[r][tx] = W[(size_t)(k0 + r) * N + n0 + tx];
  __syncthreads();
  for (int r = ty; r < 32; r += 8)
    Wt[(size_t)(n0 + r) * K + k0 + tx] = (bf16_t)tile[tx][r];
}

// ---------------- QKV GEMM: C[8192,3072] = Xb[8192,1024] @ Wt[3072,1024]^T ----------------
// Q,K written [b,h,s,d] (Q pre-scaled by QSCALE); V written TRANSPOSED [b,h,d,s].
__global__ __launch_bounds__(256) void gemm_qkv_kernel(
    const bf16_t* __restrict__ A, const bf16_t* __restrict__ Bt,
    bf16_t* __restrict__ Qb, bf16_t* __restrict__ Kb, bf16_t* __restrict__ Vt) {
  __shared__ __align__(16) bf16_t As[128 * 32];
  __shared__ __align__(16) bf16_t Bs[128 * 32];
  const int tid = threadIdx.x;
  const int lane = tid & 63, wave = tid >> 6;
  const int quad = lane >> 4, l15 = lane & 15;
  const int wr = wave >> 1, wc = wave & 1;
  const int m0 = blockIdx.x * 128, n0 = blockIdx.y * 128;
  f32x4 acc[4][4];
  const f32x4 vzero = {0.f, 0.f, 0.f, 0.f};
#pragma unroll
  for (int i = 0; i < 4; i++)
#pragma unroll
    for (int j = 0; j < 4; j++) acc[i][j] = vzero;

  for (int kb = 0; kb < 1024; kb += 32) {
    __syncthreads();
#pragma unroll
    for (int i = 0; i < 2; i++) {
      int c = i * 256 + tid;
      int row = c >> 2, kc = c & 3;
      __builtin_amdgcn_global_load_lds(AS1(A + (size_t)(m0 + row) * 1024 + kb + kc * 8),
                                       AS3(As + c * 8), 16, 0, 0);
    }
#pragma unroll
    for (int i = 0; i < 2; i++) {
      int c = i * 256 + tid;
      int row = c >> 2, kc = c & 3;
      __builtin_amdgcn_global_load_lds(AS1(Bt + (size_t)(n0 + row) * 1024 + kb + kc * 8),
                                       AS3(Bs + c * 8), 16, 0, 0);
    }
    __builtin_amdgcn_s_waitcnt(0);
    __syncthreads();
    bf16x8 af[4], bfr[4];
#pragma unroll
    for (int t = 0; t < 4; t++) {
      af[t]  = *(const bf16x8*)(As + (wr * 64 + t * 16 + l15) * 32 + quad * 8);
      bfr[t] = *(const bf16x8*)(Bs + (wc * 64 + t * 16 + l15) * 32 + quad * 8);
    }
#pragma unroll
    for (int mt = 0; mt < 4; mt++)
#pragma unroll
      for (int nt = 0; nt < 4; nt++)
        acc[mt][nt] = __builtin_amdgcn_mfma_f32_16x16x32_bf16(af[mt], bfr[nt], acc[mt][nt], 0, 0, 0);
  }
  // C layout: col=lane&15, row=quad*4+reg
#pragma unroll
  for (int nt = 0; nt < 4; nt++) {
    int gn = n0 + wc * 64 + nt * 16 + l15;
    int which = gn >> 10;   // 0=Q, 1=K, 2=V (uniform across lanes per nt)
    int rem = gn & 1023;
    int hh = rem >> 6, dd = rem & 63;
    if (which == 2) {
      // V transposed: Vt[b][h][dd][s], r-dim is consecutive s -> 8B vector store
#pragma unroll
      for (int mt = 0; mt < 4; mt++) {
        int gm0 = m0 + wr * 64 + mt * 16 + quad * 4;
        int b = gm0 >> 11, s = gm0 & 2047;
        bf16x4 o;
#pragma unroll
        for (int r = 0; r < 4; r++) o[r] = (bf16_t)acc[mt][nt][r];
        *(bf16x4*)(Vt + ((size_t)((b << 4) + hh) * 64 + dd) * 2048 + s) = o;
      }
    } else {
      bf16_t* dst = (which == 0) ? Qb : Kb;
      float scl = (which == 0) ? QSCALE : 1.0f;
#pragma unroll
      for (int mt = 0; mt < 4; mt++) {
#pragma unroll
        for (int r = 0; r < 4; r++) {
          int gm = m0 + wr * 64 + mt * 16 + quad * 4 + r;
          int b = gm >> 11, s = gm & 2047;
          dst[((size_t)((b << 4) + hh) * 2048 + s) * 64 + dd] = (bf16_t)(acc[mt][nt][r] * scl);
        }
      }
    }
  }
}

// pack two f32 into one u32 of 2 bf16
__device__ inline unsigned pack_bf16x2(float a, float b) {
  unsigned short lo = __builtin_bit_cast(unsigned short, (bf16_t)a);
  unsigned short hi = __builtin_bit_cast(unsigned short, (bf16_t)b);
  return (unsigned)lo | ((unsigned)hi << 16);
}

// ---------------- Flash attention, causal, no-max softmax, in-register P ----------------
// Round-4 structure (verified 74 us): 1024 blocks = 64 bh x 16 Q-tiles, bh in low
// 6 bits (per-bh XCD L2 affinity: FETCH 146->25 MB); KVBLK=64, LDS 32 KB, 4
// blocks/CU; swapped QK^T with sigma-permuted K rows -> softmax/mask/pack fully
// in-register, L on the matrix pipe. Round-5's body fusion REVERTED (spilled:
// WRITE_SIZE 16->42 MB scratch traffic, +59% time).
// NEW: balanced qb permutation. With 1024 blocks on exactly 1024 slots, wall =
// max per-CU work. CU hosts blocks {i0, i0+256, i0+512, i0+768}; old qb=15-(i>>6)
// gave per-CU sums 40..28 (18% tail). perm {15..12, 8..11, 7..4, 0..3} makes every
// CU's four qbs {15-k, 8+k, 7-k, k} -> sum 30 exactly. bh bits untouched.
__global__ __launch_bounds__(256, 4) void attn_kernel(
    const bf16_t* __restrict__ Qg_, const bf16_t* __restrict__ Kg_,
    const bf16_t* __restrict__ Vtg_, bf16_t* __restrict__ ctx) {
  __shared__ __align__(16) bf16_t Ksm[2][64 * 64];  // [k][d], 16B slots XOR row&7  (8 KB each)
  __shared__ __align__(16) bf16_t Vsm[2][64 * 64];  // [d][s], 16B slots XOR d&7    (8 KB each)
  const int tid = threadIdx.x;
  const int lane = tid & 63, w = tid >> 6;
  const int l31 = lane & 31, hl = lane >> 5;
  // sigma: swap bits 2 and 3 of l31 — K A-operand row permutation
  const int krow = (l31 & 0x13) | ((l31 & 4) << 1) | ((l31 & 8) >> 1);

  const int bh = blockIdx.x & 63;          // low bits -> XCD = bh%8
  // balanced qb permutation (uniform scalar ternaries, no memory table)
  const int g = blockIdx.x >> 6;           // 0..15
  const int gr = g >> 2, gc = g & 3;
  const int qb = (gr == 0) ? (15 - gc) : (gr == 1) ? (8 + gc) : (gr == 2) ? (7 - gc) : gc;
  const int b = bh >> 4, h = bh & 15;
  const size_t base = (size_t)bh * 2048 * 64;
  const bf16_t* Qg = Qg_ + base;
  const bf16_t* Kg = Kg_ + base;
  const bf16_t* Vtg = Vtg_ + base;  // [d][s]

  // per-lane LDS element offsets (nt adds a compile-time term under unroll)
  int kadr[4];
#pragma unroll
  for (int kk = 0; kk < 4; kk++)
    kadr[kk] = (krow * 8 + ((kk * 2 + hl) ^ (krow & 7))) * 8;
  int vadr[2];
#pragma unroll
  for (int nv = 0; nv < 2; nv++) {
    const int dr = nv * 32 + l31;
    vadr[nv] = (dr * 8 + (hl ^ (dr & 7))) * 8;
  }

  auto stage_kv = [&](int bb, int jn) {
#pragma unroll
    for (int i = 0; i < 2; i++) {
      int slot = i * 256 + tid;                       // 512 16B slots = 64x64 bf16
      int row = slot >> 3, c = (slot & 7) ^ (row & 7);
      __builtin_amdgcn_global_load_lds(AS1(Kg + ((size_t)jn * 64 + row) * 64 + c * 8),
                                       AS3(&Ksm[bb][0] + slot * 8), 16, 0, 0);
    }
#pragma unroll
    for (int i = 0; i < 2; i++) {
      int slot = i * 256 + tid;                       // 512 16B slots = 64x64 bf16
      int d = slot >> 3, c = (slot & 7) ^ (d & 7);
      __builtin_amdgcn_global_load_lds(AS1(Vtg + (size_t)d * 2048 + jn * 64 + c * 8),
                                       AS3(&Vsm[bb][0] + slot * 8), 16, 0, 0);
    }
  };

  bf16x8 bone;
#pragma unroll
  for (int e = 0; e < 8; e++) bone[e] = (bf16_t)1.0f;
  f32x16 zc;
#pragma unroll
  for (int e = 0; e < 16; e++) zc[e] = 0.f;

  const int J = 2 * (qb + 1);              // 64-wide KV iters
  const int qrel = qb * 128 + w * 32;      // wave's first q row (global)
  const int qg = qrel + l31;               // this lane's q-row (softmax axis)

  // Q fragments (B-operand of 32x32x16): n=l31=q, k = hl*8+e
  bf16x8 aq[4];
#pragma unroll
  for (int kk = 0; kk < 4; kk++)
    aq[kk] = *(const bf16x8*)(Qg + (size_t)qg * 64 + kk * 16 + hl * 8);

  f32x16 Oacc[2], Lacc;
#pragma unroll
  for (int e = 0; e < 16; e++) { Oacc[0][e] = 0.f; Oacc[1][e] = 0.f; Lacc[e] = 0.f; }

  int cur = 0;
  stage_kv(0, 0);

  for (int j = 0; j < J; j++) {
    // stage-j DMA (issued last iter, hidden under compute) must be in LDS;
    // per-thread vmcnt(0) BEFORE the barrier covers other waves' reads too
    asm volatile("s_waitcnt vmcnt(0)" ::: "memory");
    __syncthreads();
    if (j + 1 < J) stage_kv(cur ^ 1, j + 1);  // flies during compute

    const bf16_t* Kb = &Ksm[cur][0];
    const bf16_t* Vb = &Vsm[cur][0];
    const int k0 = j * 64;

    auto nt_body = [&](int nt, bool masked) {
      // S^T[k][q=l31] = sum_d K[k][d] * Q[q][d], k rows sigma-permuted
      __builtin_amdgcn_s_setprio(1);
      bf16x8 ak = *(const bf16x8*)(Kb + nt * 2048 + kadr[0]);
      f32x16 sc = __builtin_amdgcn_mfma_f32_32x32x16_bf16(ak, aq[0], zc, 0, 0, 0);
#pragma unroll
      for (int kk = 1; kk < 4; kk++) {
        ak = *(const bf16x8*)(Kb + nt * 2048 + kadr[kk]);
        sc = __builtin_amdgcn_mfma_f32_32x32x16_bf16(ak, aq[kk], sc, 0, 0, 0);
      }
      __builtin_amdgcn_s_setprio(0);

      // lane's 16 values sit at k-offs hl*8 + (r&7) + 16*(r>>3)  (thanks to sigma)
      float p[16];
#pragma unroll
      for (int r = 0; r < 16; r++) {
        const int koff = hl * 8 + (r & 7) + 16 * (r >> 3);
        p[r] = (masked && (koff > l31)) ? 0.f : __builtin_exp2f(sc[r]);
      }

      // P bf16 A-fragments, directly in-lane (no cross-lane ops)
      u32x4 w0, w1;
      w0[0] = pack_bf16x2(p[0], p[1]);   w0[1] = pack_bf16x2(p[2], p[3]);
      w0[2] = pack_bf16x2(p[4], p[5]);   w0[3] = pack_bf16x2(p[6], p[7]);
      w1[0] = pack_bf16x2(p[8], p[9]);   w1[1] = pack_bf16x2(p[10], p[11]);
      w1[2] = pack_bf16x2(p[12], p[13]); w1[3] = pack_bf16x2(p[14], p[15]);
      bf16x8 pa0 = __builtin_bit_cast(bf16x8, w0);  // k-offs nt*32 + 0..15
      bf16x8 pa1 = __builtin_bit_cast(bf16x8, w1);  // k-offs nt*32 + 16..31

      __builtin_amdgcn_s_setprio(1);
      // L row-sums on the matrix pipe; C rows == Oacc rows (no redistribution)
      Lacc = __builtin_amdgcn_mfma_f32_32x32x16_bf16(pa0, bone, Lacc, 0, 0, 0);
      Lacc = __builtin_amdgcn_mfma_f32_32x32x16_bf16(pa1, bone, Lacc, 0, 0, 0);
      // O += P @ V  (B-operand: n=l31=dv, k=hl*8+e along s)
#pragma unroll
      for (int nv = 0; nv < 2; nv++) {
        bf16x8 bv0 = *(const bf16x8*)(Vb + (vadr[nv] ^ ((nt * 4 + 0) * 8)));
        Oacc[nv] = __builtin_amdgcn_mfma_f32_32x32x16_bf16(pa0, bv0, Oacc[nv], 0, 0, 0);
        bf16x8 bv1 = *(const bf16x8*)(Vb + (vadr[nv] ^ ((nt * 4 + 2) * 8)));
        Oacc[nv] = __builtin_amdgcn_mfma_f32_32x32x16_bf16(pa1, bv1, Oacc[nv], 0, 0, 0);
      }
      __builtin_amdgcn_s_setprio(0);
    };

#pragma unroll
    for (int nt = 0; nt < 2; nt++) {
      const int kk0 = k0 + nt * 32;
      if (kk0 <= qrel) nt_body(nt, kk0 == qrel);  // kk0 > qrel: fully masked -> skip
    }
    cur ^= 1;
  }

  // epilogue: Lacc rows coincide with Oacc rows -> direct rcp, no shuffles/LDS
#pragma unroll
  for (int r = 0; r < 16; r++) {
    const int crow = (r & 3) + 8 * (r >> 2) + 4 * hl;
    const float rl = __builtin_amdgcn_rcpf(Lacc[r]);
    const int qrow = qb * 128 + w * 32 + crow;
#pragma unroll
    for (int nv = 0; nv < 2; nv++)
      ctx[((size_t)b * 2048 + qrow) * 1024 + h * 64 + nv * 32 + l31] =
          (bf16_t)(Oacc[nv][r] * rl);
  }
}

// ---------------- out proj: out[8192,1024] = ctx @ Wout^T + b ----------------
__global__ __launch_bounds__(256) void gemm_out_kernel(
    const bf16_t* __restrict__ A, const bf16_t* __restrict__ Bt,
    const float* __restrict__ bias, float* __restrict__ out) {
  __shared__ __align__(16) bf16_t As[128 * 32];
  __shared__ __align__(16) bf16_t Bs[128 * 32];
  const int tid = threadIdx.x;
  const int lane = tid & 63, wave = tid >> 6;
  const int quad = lane >> 4, l15 = lane & 15;
  const int wr = wave >> 1, wc = wave & 1;
  const int m0 = blockIdx.x * 128, n0 = blockIdx.y * 128;
  f32x4 acc[4][4];
  const f32x4 vzero = {0.f, 0.f, 0.f, 0.f};
#pragma unroll
  for (int i = 0; i < 4; i++)
#pragma unroll
    for (int j = 0; j < 4; j++) acc[i][j] = vzero;

  for (int kb = 0; kb < 1024; kb += 32) {
    __syncthreads();
#pragma unroll
    for (int i = 0; i < 2; i++) {
      int c = i * 256 + tid;
      int row = c >> 2, kc = c & 3;
      __builtin_amdgcn_global_load_lds(AS1(A + (size_t)(m0 + row) * 1024 + kb + kc * 8),
                                       AS3(As + c * 8), 16, 0, 0);
    }
#pragma unroll
    for (int i = 0; i < 2; i++) {
      int c = i * 256 + tid;
      int row = c >> 2, kc = c & 3;
      __builtin_amdgcn_global_load_lds(AS1(Bt + (size_t)(n0 + row) * 1024 + kb + kc * 8),
                                       AS3(Bs + c * 8), 16, 0, 0);
    }
    __builtin_amdgcn_s_waitcnt(0);
    __syncthreads();
    bf16x8 af[4], bfr[4];
#pragma unroll
    for (int t = 0; t < 4; t++) {
      af[t]  = *(const bf16x8*)(As + (wr * 64 + t * 16 + l15) * 32 + quad * 8);
      bfr[t] = *(const bf16x8*)(Bs + (wc * 64 + t * 16 + l15) * 32 + quad * 8);
    }
#pragma unroll
    for (int mt = 0; mt < 4; mt++)
#pragma unroll
      for (int nt = 0; nt < 4; nt++)
        acc[mt][nt] = __builtin_amdgcn_mfma_f32_16x16x32_bf16(af[mt], bfr[nt], acc[mt][nt], 0, 0, 0);
  }
#pragma unroll
  for (int nt = 0; nt < 4; nt++) {
    int gn = n0 + wc * 64 + nt * 16 + l15;
    float bv = bias[gn];
#pragma unroll
    for (int mt = 0; mt < 4; mt++) {
#pragma unroll
      for (int r = 0; r < 4; r++) {
        int gm = m0 + wr * 64 + mt * 16 + quad * 4 + r;
        out[(size_t)gm * 1024 + gn] = acc[mt][nt][r] + bv;
      }
    }
  }
}

extern "C" void kernel_launch(void* const* d_in, const int* in_sizes, int n_in,
                              void* d_out, int out_size, void* d_ws, size_t ws_size,
                              hipStream_t stream) {
  (void)in_sizes; (void)n_in; (void)out_size; (void)ws_size;
  const float* X     = (const float*)d_in[0];  // [4,2048,1024]
  const float* W_qkv = (const float*)d_in[1];  // [1024,3072]
  const float* W_out = (const float*)d_in[2];  // [1024,1024]
  const float* b_out = (const float*)d_in[3];  // [1024]
  float* out = (float*)d_out;                  // [4,2048,1024] fp32

  char* ws = (char*)d_ws;
  bf16_t* Xb    = (bf16_t*)(ws);               // 16 MB
  bf16_t* Wqkvt = (bf16_t*)(ws + 16777216);    // 6 MB   [3072][1024]
  bf16_t* Woutt = (bf16_t*)(ws + 23068672);    // 2 MB   [1024][1024]
  bf16_t* Qb    = (bf16_t*)(ws + 25165824);    // 16 MB  [b,h,s,d]
  bf16_t* Kb    = (bf16_t*)(ws + 41943040);    // 16 MB  [b,h,s,d]
  bf16_t* Vt    = (bf16_t*)(ws + 58720256);    // 16 MB  [b,h,d,s] (written directly by GEMM)
  bf16_t* ctx   = (bf16_t*)(ws + 75497472);    // 16 MB  [b,s,1024]

  cast_x_kernel<<<8192, 256, 0, stream>>>(X, Xb);
  transpose_cast_kernel<<<dim3(96, 32), dim3(32, 8), 0, stream>>>(W_qkv, Wqkvt, 1024, 3072);
  transpose_cast_kernel<<<dim3(32, 32), dim3(32, 8), 0, stream>>>(W_out, Woutt, 1024, 1024);
  gemm_qkv_kernel<<<dim3(64, 24), 256, 0, stream>>>(Xb, Wqkvt, Qb, Kb, Vt);
  attn_kernel<<<dim3(1024), 256, 0, stream>>>(Qb, Kb, Vt, ctx);
  gemm_out_kernel<<<dim3(64, 8), 256, 0, stream>>>(ctx, Woutt, b_out, out);
}